// Round 15
// baseline (179.241 us; speedup 1.0000x reference)
//
#include <hip/hip_runtime.h>
#include <hip/hip_bf16.h>

typedef float    f32x4  __attribute__((ext_vector_type(4)));
typedef float    f32x16 __attribute__((ext_vector_type(16)));
typedef _Float16 f16x8  __attribute__((ext_vector_type(8)));
typedef _Float16 f16x2  __attribute__((ext_vector_type(2)));

#define VP 258   // vlds co-pitch (conflict-free both phases)
#define XP 136   // xs plane-pitch: col stride 272B = 17x16B -> b128-aligned A-frags
#define AP 258   // act pitch

// ---------------------------------------------------------------------------
// Kernel 0: W [144][256] f32 -> wt [co(256)][tap(9)][kd(16)] fp16
// ---------------------------------------------------------------------------
__global__ __launch_bounds__(256) void prep_wt_kernel(
    const float* __restrict__ W, _Float16* __restrict__ wt)
{
    const int k = blockIdx.x;      // 0..143 ; kd = k/9, tap = k%9
    const int t = threadIdx.x;     // co
    wt[t * 144 + (k % 9) * 16 + (k / 9)] = (_Float16)W[k * 256 + t];
}

// ---------------------------------------------------------------------------
// Persistent fused kernel: 256 blocks (1/CU), 1024 threads, 3-4 jobs each.
// Job = XCD-swizzled (b,h). Next job's x prefetched to registers during
// current job's routing (T14 across jobs). W frags persistent in VGPRs.
// ---------------------------------------------------------------------------
__global__ __launch_bounds__(1024) void fused_kernel(
    const float* __restrict__ x, const _Float16* __restrict__ wt,
    const float* __restrict__ bias, float* __restrict__ out)
{
    const int kblk = blockIdx.x;   // 0..255
    const int t    = threadIdx.x;  // 0..1023
    const int njobs = (kblk < 192) ? 4 : 3;

    __shared__ _Float16 vlds[8 * 30 * VP];          // 123,840 B
    __shared__ union {
        _Float16 xs[3][36][XP];                     // 29,376 B (conv phase)
        struct {                                    // routing phase
            _Float16 route16[8 * 16 * 32];          //  8,192 B
            _Float16 act16[30 * AP];                // 15,480 B
            float    s2buf[4][256];                 //  4,096 B
        } rt;
    } u;                                            // total 153,216 B

    // ---- loop-invariant thread mappings
    const int lane = t & 63, wv = t >> 6;
    const int l31 = lane & 31, kb = lane >> 5;
    const int ct = wv >> 1, dh = wv & 1;            // conv: co-tile, d-half
    const int oaC = ct * 32 + l31;

    const int oa = t & 255, wq = t >> 8;            // phase B: (oa, w-quarter)
    const int o = oa >> 4;
    const int wbase = wq * 8;
    const int nw = (wq == 3) ? 6 : 8;
    const float bias_t = bias[oa];
    const int iA = t / 30, wA = t - iA * 30;        // phase A/C (t<240)

    // stage granule indices (invariant): granules q0 = t, q1 = t+1024
    const bool ok1 = (t < 512);
    const int g0 = t / 24,          p00 = g0 * 2;
    const int rem0 = t - g0 * 24,   r0 = rem0 >> 3, c40 = rem0 & 7;
    const int q1 = t + 1024;
    const int g1 = q1 / 24,         p01 = g1 * 2;
    const int rem1 = q1 - g1 * 24,  r1 = rem1 >> 3, c41 = rem1 & 7;

    // ---- persistent W fragments (loaded once)
    f16x8 bf[9];
    {
        const _Float16* wp = wt + (size_t)oaC * 144 + kb * 8;
        #pragma unroll
        for (int s = 0; s < 9; ++s) bf[s] = *(const f16x8*)(wp + s * 16);
    }

    // ---- prefetch job 0
    f32x4 v00, v01, v10, v11;
    {
        const int j = kblk;
        const int wid = (j & 7) * 120 + (j >> 3);
        const int b = wid / 30, h = wid - 30 * b;
        const float* xb = x + (size_t)b * 131072;
        v00 = *(const f32x4*)(xb + p00 * 1024 + (h + r0) * 32 + c40 * 4);
        v01 = *(const f32x4*)(xb + (p00 + 1) * 1024 + (h + r0) * 32 + c40 * 4);
        if (ok1) {
            v10 = *(const f32x4*)(xb + p01 * 1024 + (h + r1) * 32 + c41 * 4);
            v11 = *(const f32x4*)(xb + (p01 + 1) * 1024 + (h + r1) * 32 + c41 * 4);
        }
    }

    for (int jj = 0; jj < njobs; ++jj) {
        const int j = kblk + jj * 256;
        const int wid = (j & 7) * 120 + (j >> 3);
        const int b = wid / 30, h = wid - 30 * b;

        if (jj > 0) __syncthreads();   // xs/rt union guard (prior routing done)

        // ---- commit stage from prefetched registers (LDS-only)
        if (t < 768) {                 // zero-fill cols 32..35
            int r = t / 256, rem = t - r * 256;
            int c = rem >> 6, pz = (rem & 63) * 2;
            *(f16x2*)&u.xs[r][32 + c][pz] = f16x2{(_Float16)0.f, (_Float16)0.f};
        }
        #pragma unroll
        for (int c = 0; c < 4; ++c)
            *(f16x2*)&u.xs[r0][c40 * 4 + c][p00] = f16x2{(_Float16)v00[c], (_Float16)v01[c]};
        if (ok1) {
            #pragma unroll
            for (int c = 0; c < 4; ++c)
                *(f16x2*)&u.xs[r1][c41 * 4 + c][p01] = f16x2{(_Float16)v10[c], (_Float16)v11[c]};
        }
        __syncthreads();

        // ---- conv: wave = (ct, dh); A-frags single b128; votes -> vlds
        #pragma unroll
        for (int dd = 0; dd < 4; ++dd) {
            f32x16 acc = {};
            #pragma unroll
            for (int s = 0; s < 9; ++s) {
                const int kh = s / 3, kw = s - 3 * (s / 3);
                f16x8 af = *(const f16x8*)&u.xs[kh][l31 + kw][dh * 64 + dd * 16 + kb * 8];
                acc = __builtin_amdgcn_mfma_f32_32x32x16_f16(af, bf[s], acc, 0, 0, 0);
            }
            const int d = dh * 4 + dd;
            #pragma unroll
            for (int r = 0; r < 16; ++r) {
                const int wr = (r & 3) + 8 * (r >> 2) + 4 * kb;
                if (wr < 30) vlds[(d * 30 + wr) * VP + oaC] = (_Float16)acc[r];
            }
        }
        __syncthreads();

        // ---- issue next job's x prefetch (hides under routing)
        if (jj + 1 < njobs) {
            const int jn = kblk + (jj + 1) * 256;
            const int widn = (jn & 7) * 120 + (jn >> 3);
            const int bn = widn / 30, hn = widn - 30 * bn;
            const float* xb = x + (size_t)bn * 131072;
            v00 = *(const f32x4*)(xb + p00 * 1024 + (hn + r0) * 32 + c40 * 4);
            v01 = *(const f32x4*)(xb + (p00 + 1) * 1024 + (hn + r0) * 32 + c40 * 4);
            if (ok1) {
                v10 = *(const f32x4*)(xb + p01 * 1024 + (hn + r1) * 32 + c41 * 4);
                v11 = *(const f32x4*)(xb + (p01 + 1) * 1024 + (hn + r1) * 32 + c41 * 4);
            }
        }

        // ---- routing (r14 structure)
        float lreg[16];
        float pre[8];
        float scale = 0.f;

        for (int it = 0; it < 3; ++it) {
            // Phase A (it>0): route = softmax_o(lreg); threads (i,w)
            if (it > 0) {
                if (t < 240) {
                    float m = lreg[0];
                    #pragma unroll
                    for (int oo = 1; oo < 16; ++oo) m = fmaxf(m, lreg[oo]);
                    float e[16], ssum = 0.f;
                    #pragma unroll
                    for (int oo = 0; oo < 16; ++oo) { e[oo] = __expf(lreg[oo] - m); ssum += e[oo]; }
                    float inv = 1.f / ssum;
                    #pragma unroll
                    for (int oo = 0; oo < 16; ++oo)
                        u.rt.route16[(iA * 16 + oo) * 32 + wA] = (_Float16)(e[oo] * inv);
                }
                __syncthreads();
            }

            // Phase B: thread (oa, wq) over its w-quarter
            #pragma unroll
            for (int w = 0; w < 8; ++w) pre[w] = bias_t;
            if (it == 0) {
                #pragma unroll
                for (int i = 0; i < 8; ++i) {
                    const _Float16* vrow = &vlds[(i * 30 + wbase) * VP + oa];
                    #pragma unroll
                    for (int w = 0; w < 8; ++w)
                        if (w < nw) pre[w] = fmaf(0.0625f, (float)vrow[w * VP], pre[w]);
                }
            } else {
                #pragma unroll
                for (int i = 0; i < 8; ++i) {
                    const _Float16* vrow = &vlds[(i * 30 + wbase) * VP + oa];
                    const _Float16* rr   = &u.rt.route16[(i * 16 + o) * 32 + wbase];
                    #pragma unroll
                    for (int w = 0; w < 8; ++w)
                        if (w < nw) pre[w] = fmaf((float)rr[w], (float)vrow[w * VP], pre[w]);
                }
            }
            float s2p = 0.f;
            #pragma unroll
            for (int w = 0; w < 8; ++w)
                if (w < nw) s2p = fmaf(pre[w], pre[w], s2p);
            u.rt.s2buf[wq][oa] = s2p;
            __syncthreads();
            float s2 = u.rt.s2buf[0][oa] + u.rt.s2buf[1][oa]
                     + u.rt.s2buf[2][oa] + u.rt.s2buf[3][oa];
            scale = s2 / ((1.f + s2) * sqrtf(s2 + 1e-7f));

            if (it < 2) {
                #pragma unroll
                for (int w = 0; w < 8; ++w)
                    if (w < nw) u.rt.act16[(wbase + w) * AP + oa] = (_Float16)(scale * pre[w]);
                __syncthreads();
                // Phase C: thread (i,w) t<240: lreg[o] (+)= sum_a v*act
                if (t < 240) {
                    const _Float16* vrow = &vlds[(iA * 30 + wA) * VP];
                    const _Float16* arow = &u.rt.act16[wA * AP];
                    #pragma unroll
                    for (int oo = 0; oo < 16; ++oo) {
                        float s = 0.f;
                        #pragma unroll
                        for (int kk = 0; kk < 8; ++kk) {
                            f16x2 v2 = *(const f16x2*)&vrow[oo * 16 + 2 * kk];
                            f16x2 a2 = *(const f16x2*)&arow[oo * 16 + 2 * kk];
#if __has_builtin(__builtin_amdgcn_fdot2)
                            s = __builtin_amdgcn_fdot2(v2, a2, s, false);
#else
                            s = fmaf((float)v2[0], (float)a2[0], s);
                            s = fmaf((float)v2[1], (float)a2[1], s);
#endif
                        }
                        if (it == 0) lreg[oo] = s; else lreg[oo] += s;
                    }
                }
                // no barrier: next A runs on the same 240 threads (lreg in regs)
            }
        }

        // ---- output: out[b,h,w,o,a]; lanes consecutive oa -> coalesced
        float* ob = out + (size_t)((b * 30 + h) * 30) * 256;
        #pragma unroll
        for (int w = 0; w < 8; ++w)
            if (w < nw) ob[(wbase + w) * 256 + oa] = scale * pre[w];
    }
}

extern "C" void kernel_launch(void* const* d_in, const int* in_sizes, int n_in,
                              void* d_out, int out_size, void* d_ws, size_t ws_size,
                              hipStream_t stream)
{
    const float* x    = (const float*)d_in[0];  // [32,32,32,8,16] (raw-reshape view)
    const float* Wt   = (const float*)d_in[1];  // [16,3,3,1,256] = [144][256]
    const float* bias = (const float*)d_in[2];  // [16,16,1,1]
    float* out = (float*)d_out;                 // [32,30,30,16,16]
    _Float16* wt_h = (_Float16*)d_ws;           // [256][144] fp16 = 73,728 B

    prep_wt_kernel<<<dim3(144), 256, 0, stream>>>(Wt, wt_h);
    fused_kernel<<<dim3(256), 1024, 0, stream>>>(x, wt_h, bias, out);
}

// Round 16
// 164.796 us; speedup vs baseline: 1.0877x; 1.0877x over previous
//
#include <hip/hip_runtime.h>
#include <hip/hip_bf16.h>

typedef float    f32x4  __attribute__((ext_vector_type(4)));
typedef float    f32x16 __attribute__((ext_vector_type(16)));
typedef _Float16 f16x8  __attribute__((ext_vector_type(8)));
typedef _Float16 f16x4  __attribute__((ext_vector_type(4)));
typedef _Float16 f16x2  __attribute__((ext_vector_type(2)));

#define VP 258   // vlds co-pitch (conflict-free both phases)
#define XP 132   // xs plane-pitch: lane stride 66 words === 2 mod 32 -> 2-way (free)
#define AP 258   // act pitch

// ---------------------------------------------------------------------------
// Kernel 0: W [144][256] f32 -> wt [co(256)][tap(9)][kd(16)] fp16
// ---------------------------------------------------------------------------
__global__ __launch_bounds__(256) void prep_wt_kernel(
    const float* __restrict__ W, _Float16* __restrict__ wt)
{
    const int k = blockIdx.x;      // 0..143 ; kd = k/9, tap = k%9
    const int t = threadIdx.x;     // co
    wt[t * 144 + (k % 9) * 16 + (k / 9)] = (_Float16)W[k * 256 + t];
}

// ---------------------------------------------------------------------------
// Persistent fused kernel: 256 blocks (1/CU), 1024 threads, 3-4 jobs each.
// Job = XCD-swizzled (b,h). Next job's x prefetched into registers during
// current job's routing. W frags reloaded per job (L2-hot, keeps pressure low).
// ---------------------------------------------------------------------------
__global__ __launch_bounds__(1024, 4) void fused_kernel(
    const float* __restrict__ x, const _Float16* __restrict__ wt,
    const float* __restrict__ bias, float* __restrict__ out)
{
    const int kblk = blockIdx.x;   // 0..255
    const int t    = threadIdx.x;  // 0..1023
    const int njobs = (kblk < 192) ? 4 : 3;

    __shared__ _Float16 vlds[8 * 30 * VP];          // 123,840 B
    __shared__ union {
        _Float16 xs[3][36][XP];                     // 28,512 B (conv phase)
        struct {                                    // routing phase
            _Float16 route16[8 * 16 * 32];          //  8,192 B
            _Float16 act16[30 * AP];                // 15,480 B
            float    s2buf[4][256];                 //  4,096 B
        } rt;
    } u;                                            // total 152,352 B

    // ---- loop-invariant thread mappings
    const int lane = t & 63, wv = t >> 6;
    const int l31 = lane & 31, kb = lane >> 5;
    const int ct = wv >> 1, dh = wv & 1;            // conv: co-tile, d-half
    const int oaC = ct * 32 + l31;

    const int oa = t & 255, wq = t >> 8;            // phase B: (oa, w-quarter)
    const int o = oa >> 4;
    const int wbase = wq * 8;
    const int nw = (wq == 3) ? 6 : 8;
    const float bias_t = bias[oa];
    const int iA = t / 30, wA = t - iA * 30;        // phase A/C (t<240)

    // stage granule indices (invariant): granules q0 = t, q1 = t+1024
    const bool ok1 = (t < 512);
    const int g0 = t / 24,          p00 = g0 * 2;
    const int rem0 = t - g0 * 24,   r0 = rem0 >> 3, c40 = rem0 & 7;
    const int q1 = t + 1024;
    const int g1 = q1 / 24,         p01 = g1 * 2;
    const int rem1 = q1 - g1 * 24,  r1 = rem1 >> 3, c41 = rem1 & 7;

    // ---- prefetch job 0
    f32x4 v00, v01, v10, v11;
    {
        const int j = kblk;
        const int wid = (j & 7) * 120 + (j >> 3);
        const int b = wid / 30, h = wid - 30 * b;
        const float* xb = x + (size_t)b * 131072;
        v00 = *(const f32x4*)(xb + p00 * 1024 + (h + r0) * 32 + c40 * 4);
        v01 = *(const f32x4*)(xb + (p00 + 1) * 1024 + (h + r0) * 32 + c40 * 4);
        if (ok1) {
            v10 = *(const f32x4*)(xb + p01 * 1024 + (h + r1) * 32 + c41 * 4);
            v11 = *(const f32x4*)(xb + (p01 + 1) * 1024 + (h + r1) * 32 + c41 * 4);
        }
    }

    for (int jj = 0; jj < njobs; ++jj) {
        const int j = kblk + jj * 256;
        const int wid = (j & 7) * 120 + (j >> 3);
        const int b = wid / 30, h = wid - 30 * b;

        if (jj > 0) __syncthreads();   // xs/rt union guard (prior routing done)

        // ---- commit stage from prefetched registers (LDS-only)
        if (t < 768) {                 // zero-fill cols 32..35
            int r = t / 256, rem = t - r * 256;
            int c = rem >> 6, pz = (rem & 63) * 2;
            *(f16x2*)&u.xs[r][32 + c][pz] = f16x2{(_Float16)0.f, (_Float16)0.f};
        }
        #pragma unroll
        for (int c = 0; c < 4; ++c)
            *(f16x2*)&u.xs[r0][c40 * 4 + c][p00] = f16x2{(_Float16)v00[c], (_Float16)v01[c]};
        if (ok1) {
            #pragma unroll
            for (int c = 0; c < 4; ++c)
                *(f16x2*)&u.xs[r1][c41 * 4 + c][p01] = f16x2{(_Float16)v10[c], (_Float16)v11[c]};
        }
        __syncthreads();

        // ---- conv: wave = (ct, dh); W frags loaded per job (L2-hot)
        {
            f16x8 bf[9];
            const _Float16* wp = wt + (size_t)oaC * 144 + kb * 8;
            #pragma unroll
            for (int s = 0; s < 9; ++s) bf[s] = *(const f16x8*)(wp + s * 16);

            #pragma unroll
            for (int dd = 0; dd < 4; ++dd) {
                f32x16 acc = {};
                #pragma unroll
                for (int s = 0; s < 9; ++s) {
                    const int kh = s / 3, kw = s - 3 * (s / 3);
                    const _Float16* ap = &u.xs[kh][l31 + kw][dh * 64 + dd * 16 + kb * 8];
                    f16x4 lo = *(const f16x4*)(ap);
                    f16x4 hi = *(const f16x4*)(ap + 4);
                    f16x8 af = __builtin_shufflevector(lo, hi, 0, 1, 2, 3, 4, 5, 6, 7);
                    acc = __builtin_amdgcn_mfma_f32_32x32x16_f16(af, bf[s], acc, 0, 0, 0);
                }
                const int d = dh * 4 + dd;
                #pragma unroll
                for (int r = 0; r < 16; ++r) {
                    const int wr = (r & 3) + 8 * (r >> 2) + 4 * kb;
                    if (wr < 30) vlds[(d * 30 + wr) * VP + oaC] = (_Float16)acc[r];
                }
            }
        }
        __syncthreads();

        // ---- issue next job's x prefetch (hides under routing)
        if (jj + 1 < njobs) {
            const int jn = kblk + (jj + 1) * 256;
            const int widn = (jn & 7) * 120 + (jn >> 3);
            const int bn = widn / 30, hn = widn - 30 * bn;
            const float* xb = x + (size_t)bn * 131072;
            v00 = *(const f32x4*)(xb + p00 * 1024 + (hn + r0) * 32 + c40 * 4);
            v01 = *(const f32x4*)(xb + (p00 + 1) * 1024 + (hn + r0) * 32 + c40 * 4);
            if (ok1) {
                v10 = *(const f32x4*)(xb + p01 * 1024 + (hn + r1) * 32 + c41 * 4);
                v11 = *(const f32x4*)(xb + (p01 + 1) * 1024 + (hn + r1) * 32 + c41 * 4);
            }
        }

        // ---- routing (r14 structure)
        float lreg[16];
        float pre[8];
        float scale = 0.f;

        for (int it = 0; it < 3; ++it) {
            // Phase A (it>0): route = softmax_o(lreg); threads (i,w)
            if (it > 0) {
                if (t < 240) {
                    float m = lreg[0];
                    #pragma unroll
                    for (int oo = 1; oo < 16; ++oo) m = fmaxf(m, lreg[oo]);
                    float e[16], ssum = 0.f;
                    #pragma unroll
                    for (int oo = 0; oo < 16; ++oo) { e[oo] = __expf(lreg[oo] - m); ssum += e[oo]; }
                    float inv = 1.f / ssum;
                    #pragma unroll
                    for (int oo = 0; oo < 16; ++oo)
                        u.rt.route16[(iA * 16 + oo) * 32 + wA] = (_Float16)(e[oo] * inv);
                }
                __syncthreads();
            }

            // Phase B: thread (oa, wq) over its w-quarter
            #pragma unroll
            for (int w = 0; w < 8; ++w) pre[w] = bias_t;
            if (it == 0) {
                #pragma unroll
                for (int i = 0; i < 8; ++i) {
                    const _Float16* vrow = &vlds[(i * 30 + wbase) * VP + oa];
                    #pragma unroll
                    for (int w = 0; w < 8; ++w)
                        if (w < nw) pre[w] = fmaf(0.0625f, (float)vrow[w * VP], pre[w]);
                }
            } else {
                #pragma unroll
                for (int i = 0; i < 8; ++i) {
                    const _Float16* vrow = &vlds[(i * 30 + wbase) * VP + oa];
                    const _Float16* rr   = &u.rt.route16[(i * 16 + o) * 32 + wbase];
                    #pragma unroll
                    for (int w = 0; w < 8; ++w)
                        if (w < nw) pre[w] = fmaf((float)rr[w], (float)vrow[w * VP], pre[w]);
                }
            }
            float s2p = 0.f;
            #pragma unroll
            for (int w = 0; w < 8; ++w)
                if (w < nw) s2p = fmaf(pre[w], pre[w], s2p);
            u.rt.s2buf[wq][oa] = s2p;
            __syncthreads();
            float s2 = u.rt.s2buf[0][oa] + u.rt.s2buf[1][oa]
                     + u.rt.s2buf[2][oa] + u.rt.s2buf[3][oa];
            scale = s2 / ((1.f + s2) * sqrtf(s2 + 1e-7f));

            if (it < 2) {
                #pragma unroll
                for (int w = 0; w < 8; ++w)
                    if (w < nw) u.rt.act16[(wbase + w) * AP + oa] = (_Float16)(scale * pre[w]);
                __syncthreads();
                // Phase C: thread (i,w) t<240: lreg[o] (+)= sum_a v*act
                if (t < 240) {
                    const _Float16* vrow = &vlds[(iA * 30 + wA) * VP];
                    const _Float16* arow = &u.rt.act16[wA * AP];
                    #pragma unroll
                    for (int oo = 0; oo < 16; ++oo) {
                        float s = 0.f;
                        #pragma unroll
                        for (int kk = 0; kk < 8; ++kk) {
                            f16x2 v2 = *(const f16x2*)&vrow[oo * 16 + 2 * kk];
                            f16x2 a2 = *(const f16x2*)&arow[oo * 16 + 2 * kk];
#if __has_builtin(__builtin_amdgcn_fdot2)
                            s = __builtin_amdgcn_fdot2(v2, a2, s, false);
#else
                            s = fmaf((float)v2[0], (float)a2[0], s);
                            s = fmaf((float)v2[1], (float)a2[1], s);
#endif
                        }
                        if (it == 0) lreg[oo] = s; else lreg[oo] += s;
                    }
                }
                // no barrier: next A runs on the same 240 threads (lreg in regs)
            }
        }

        // ---- output: out[b,h,w,o,a]; lanes consecutive oa -> coalesced
        float* ob = out + (size_t)((b * 30 + h) * 30) * 256;
        #pragma unroll
        for (int w = 0; w < 8; ++w)
            if (w < nw) ob[(wbase + w) * 256 + oa] = scale * pre[w];
    }
}

extern "C" void kernel_launch(void* const* d_in, const int* in_sizes, int n_in,
                              void* d_out, int out_size, void* d_ws, size_t ws_size,
                              hipStream_t stream)
{
    const float* x    = (const float*)d_in[0];  // [32,32,32,8,16] (raw-reshape view)
    const float* Wt   = (const float*)d_in[1];  // [16,3,3,1,256] = [144][256]
    const float* bias = (const float*)d_in[2];  // [16,16,1,1]
    float* out = (float*)d_out;                 // [32,30,30,16,16]
    _Float16* wt_h = (_Float16*)d_ws;           // [256][144] fp16 = 73,728 B

    prep_wt_kernel<<<dim3(144), 256, 0, stream>>>(Wt, wt_h);
    fused_kernel<<<dim3(256), 1024, 0, stream>>>(x, wt_h, bias, out);
}

// Round 17
// 67.612 us; speedup vs baseline: 2.6510x; 2.4374x over previous
//
#include <hip/hip_runtime.h>
#include <hip/hip_bf16.h>

typedef float    f32x2  __attribute__((ext_vector_type(2)));
typedef float    f32x4  __attribute__((ext_vector_type(4)));
typedef float    f32x16 __attribute__((ext_vector_type(16)));
typedef _Float16 f16x8  __attribute__((ext_vector_type(8)));
typedef _Float16 f16x4  __attribute__((ext_vector_type(4)));
typedef _Float16 f16x2  __attribute__((ext_vector_type(2)));

#define VP 264   // vlds co-pitch: rows 16B-aligned (528B), 33x16B ≡ 1 mod 8 -> b128-clean
#define XP 132   // xs plane-pitch: lane stride 66 words ≡ 2 mod 32 -> 2-way (free)
#define AP 264   // act16 pitch, same arithmetic as VP
#define RP 36    // route16 pitch: 72B rows (b64-aligned), 18-word stride -> conflict-free

// ---------------------------------------------------------------------------
// Kernel 0: W [144][256] f32 -> wt [co(256)][tap(9)][kd(16)] fp16
// ---------------------------------------------------------------------------
__global__ __launch_bounds__(256) void prep_wt_kernel(
    const float* __restrict__ W, _Float16* __restrict__ wt)
{
    const int k = blockIdx.x;      // 0..143 ; kd = k/9, tap = k%9
    const int t = threadIdx.x;     // co
    wt[t * 144 + (k % 9) * 16 + (k / 9)] = (_Float16)W[k * 256 + t];
}

// ---------------------------------------------------------------------------
// Fused kernel (r14 structure): block = XCD-swizzled (b,h), 1024 thr/16 waves.
// Conv: wave = (co-tile, d-half) -> votes in vlds.
// Phase B: thread = (oa-pair, w-group-of-4), f16x2 vote reads, f16x4 route.
// Phase C: 240 threads, b128 vote/act reads + fdot2. Logits in registers.
// ---------------------------------------------------------------------------
__global__ __launch_bounds__(1024, 4) void fused_kernel(
    const float* __restrict__ x, const _Float16* __restrict__ wt,
    const float* __restrict__ bias, float* __restrict__ out)
{
    // XCD swizzle: 960 blocks = 8 XCDs x 120
    const int bid = blockIdx.x;
    const int wid = (bid & 7) * 120 + (bid >> 3);
    const int b = wid / 30, h = wid - 30 * b;
    const int t = threadIdx.x;  // 0..1023

    __shared__ alignas(16) _Float16 vlds[8 * 30 * VP];   // 126,720 B
    __shared__ alignas(16) union {
        _Float16 xs[3][36][XP];                     // 28,512 B (conv phase)
        struct {                                    // routing phase
            _Float16 route16[8 * 16 * RP];          //  9,216 B
            _Float16 act16[30 * AP];                // 15,840 B
            f32x2    s2buf[8][128];                 //  8,192 B  (33,248)
        } rt;
    } u;                                            // total 159,968 B

    // ---- stage x (r14): plane-pair packed writes
    {
        const float* xb = x + (size_t)b * 131072;
        f32x4 v0[2], v1[2];
        int p0s[2], rs[2], c4s[2];
        #pragma unroll
        for (int j = 0; j < 2; ++j) {
            int q = t + j * 1024;
            bool ok = q < 1536;
            int qq = ok ? q : 0;
            int g  = qq / 24;
            p0s[j] = g * 2;
            int rem = qq - g * 24;
            rs[j] = rem >> 3; c4s[j] = rem & 7;
            if (ok) {
                v0[j] = *(const f32x4*)(xb + p0s[j] * 1024 + (h + rs[j]) * 32 + c4s[j] * 4);
                v1[j] = *(const f32x4*)(xb + (p0s[j] + 1) * 1024 + (h + rs[j]) * 32 + c4s[j] * 4);
            }
        }
        if (t < 768) {      // zero-fill cols 32..35 (plane pairs)
            int r = t / 256, rem = t - r * 256;
            int c = rem >> 6, pz = (rem & 63) * 2;
            *(f16x2*)&u.xs[r][32 + c][pz] = f16x2{(_Float16)0.f, (_Float16)0.f};
        }
        #pragma unroll
        for (int j = 0; j < 2; ++j) {
            if (t + j * 1024 < 1536) {
                #pragma unroll
                for (int c = 0; c < 4; ++c)
                    *(f16x2*)&u.xs[rs[j]][c4s[j] * 4 + c][p0s[j]] =
                        f16x2{(_Float16)v0[j][c], (_Float16)v1[j][c]};
            }
        }
    }
    __syncthreads();

    const int lane = t & 63, wv = t >> 6;   // wv 0..15
    const int l31  = lane & 31;
    const int kb   = lane >> 5;
    const int ct   = wv >> 1, dh = wv & 1;  // co-tile 0..7, d-half 0..1
    const int oaC  = ct * 32 + l31;

    // ---- conv: wave = (ct, dh): 4 d's x 9 K-steps; votes -> vlds
    {
        f16x8 bf[9];
        const _Float16* wp = wt + (size_t)oaC * 144 + kb * 8;
        #pragma unroll
        for (int s = 0; s < 9; ++s) bf[s] = *(const f16x8*)(wp + s * 16);

        #pragma unroll
        for (int dd = 0; dd < 4; ++dd) {
            f32x16 acc = {};
            #pragma unroll
            for (int s = 0; s < 9; ++s) {
                const int kh = s / 3, kw = s - 3 * (s / 3);
                const _Float16* ap = &u.xs[kh][l31 + kw][dh * 64 + dd * 16 + kb * 8];
                f16x4 lo = *(const f16x4*)(ap);
                f16x4 hi = *(const f16x4*)(ap + 4);
                f16x8 af = __builtin_shufflevector(lo, hi, 0, 1, 2, 3, 4, 5, 6, 7);
                acc = __builtin_amdgcn_mfma_f32_32x32x16_f16(af, bf[s], acc, 0, 0, 0);
            }
            const int d = dh * 4 + dd;
            #pragma unroll
            for (int r = 0; r < 16; ++r) {
                const int wr = (r & 3) + 8 * (r >> 2) + 4 * kb;
                if (wr < 30) vlds[(d * 30 + wr) * VP + oaC] = (_Float16)acc[r];
            }
        }
    }
    __syncthreads();

    // ---- routing mappings
    const int oa2 = t & 127;                // oa pair: oa = 2*oa2, 2*oa2+1
    const int wq8 = t >> 7;                 // w-group 0..7
    const int wbase = wq8 * 4;
    const int nw = (wq8 == 7) ? 2 : 4;
    const int o = oa2 >> 3;                 // both oa of pair share o
    const float biasA = bias[2 * oa2], biasB = bias[2 * oa2 + 1];
    const int iA = t / 30, wA = t - iA * 30;  // phase A/C (t<240)
    bool wok[4];
    #pragma unroll
    for (int w = 0; w < 4; ++w) wok[w] = (wbase + w) < 30;

    float lreg[16];
    float preA[4], preB[4];
    float scaleA = 0.f, scaleB = 0.f;

    for (int it = 0; it < 3; ++it) {
        // ---- Phase A (it>0): route = softmax_o(lreg); threads (i,w)
        if (it > 0) {
            if (t < 240) {
                float m = lreg[0];
                #pragma unroll
                for (int oo = 1; oo < 16; ++oo) m = fmaxf(m, lreg[oo]);
                float e[16], ssum = 0.f;
                #pragma unroll
                for (int oo = 0; oo < 16; ++oo) { e[oo] = __expf(lreg[oo] - m); ssum += e[oo]; }
                float inv = 1.f / ssum;
                #pragma unroll
                for (int oo = 0; oo < 16; ++oo)
                    u.rt.route16[(iA * 16 + oo) * RP + wA] = (_Float16)(e[oo] * inv);
            }
            __syncthreads();
        }

        // ---- Phase B: thread (oa2, wq8): pre over 4 w's for 2 oa's
        #pragma unroll
        for (int w = 0; w < 4; ++w) { preA[w] = biasA; preB[w] = biasB; }
        #pragma unroll
        for (int i = 0; i < 8; ++i) {
            f16x2 vv[4];
            #pragma unroll
            for (int w = 0; w < 4; ++w)
                vv[w] = wok[w] ? *(const f16x2*)&vlds[(i * 30 + wbase + w) * VP + 2 * oa2]
                               : f16x2{(_Float16)0.f, (_Float16)0.f};
            if (it == 0) {
                #pragma unroll
                for (int w = 0; w < 4; ++w) {
                    preA[w] = fmaf(0.0625f, (float)vv[w][0], preA[w]);
                    preB[w] = fmaf(0.0625f, (float)vv[w][1], preB[w]);
                }
            } else {
                f16x4 r4 = *(const f16x4*)&u.rt.route16[(i * 16 + o) * RP + wbase];
                #pragma unroll
                for (int w = 0; w < 4; ++w) {
                    float rw = (float)r4[w];
                    preA[w] = fmaf(rw, (float)vv[w][0], preA[w]);
                    preB[w] = fmaf(rw, (float)vv[w][1], preB[w]);
                }
            }
        }
        float s2A = 0.f, s2B = 0.f;
        #pragma unroll
        for (int w = 0; w < 4; ++w) {
            if (wok[w]) {
                s2A = fmaf(preA[w], preA[w], s2A);
                s2B = fmaf(preB[w], preB[w], s2B);
            }
        }
        u.rt.s2buf[wq8][oa2] = f32x2{s2A, s2B};
        __syncthreads();
        float sA = 0.f, sB = 0.f;
        #pragma unroll
        for (int k = 0; k < 8; ++k) {
            f32x2 p = u.rt.s2buf[k][oa2];
            sA += p[0]; sB += p[1];
        }
        scaleA = sA / ((1.f + sA) * sqrtf(sA + 1e-7f));
        scaleB = sB / ((1.f + sB) * sqrtf(sB + 1e-7f));

        if (it < 2) {
            #pragma unroll
            for (int w = 0; w < 4; ++w)
                if (wok[w])
                    *(f16x2*)&u.rt.act16[(wbase + w) * AP + 2 * oa2] =
                        f16x2{(_Float16)(scaleA * preA[w]), (_Float16)(scaleB * preB[w])};
            __syncthreads();
            // ---- Phase C: thread (i,w) t<240: lreg[o] (+)= sum_a v*act ; b128 reads
            if (t < 240) {
                const _Float16* vrow = &vlds[(iA * 30 + wA) * VP];
                const _Float16* arow = &u.rt.act16[wA * AP];
                #pragma unroll
                for (int oo = 0; oo < 16; ++oo) {
                    f16x8 v0 = *(const f16x8*)&vrow[oo * 16];
                    f16x8 v1 = *(const f16x8*)&vrow[oo * 16 + 8];
                    f16x8 a0 = *(const f16x8*)&arow[oo * 16];
                    f16x8 a1 = *(const f16x8*)&arow[oo * 16 + 8];
                    float s = 0.f;
                    #pragma unroll
                    for (int kk = 0; kk < 4; ++kk) {
#if __has_builtin(__builtin_amdgcn_fdot2)
                        s = __builtin_amdgcn_fdot2(f16x2{v0[2 * kk], v0[2 * kk + 1]},
                                                   f16x2{a0[2 * kk], a0[2 * kk + 1]}, s, false);
                        s = __builtin_amdgcn_fdot2(f16x2{v1[2 * kk], v1[2 * kk + 1]},
                                                   f16x2{a1[2 * kk], a1[2 * kk + 1]}, s, false);
#else
                        s = fmaf((float)v0[2 * kk], (float)a0[2 * kk], s);
                        s = fmaf((float)v0[2 * kk + 1], (float)a0[2 * kk + 1], s);
                        s = fmaf((float)v1[2 * kk], (float)a1[2 * kk], s);
                        s = fmaf((float)v1[2 * kk + 1], (float)a1[2 * kk + 1], s);
#endif
                    }
                    if (it == 0) lreg[oo] = s; else lreg[oo] += s;
                }
            }
            // no barrier: next A runs on the same 240 threads; the s2buf/act
            // barriers already ordered this iteration's B-reads before A-writes
        }
    }

    // ---- output: out[b,h,w,o,a]; float2 stores, lanes consecutive -> coalesced
    float* ob = out + (size_t)((b * 30 + h) * 30) * 256;
    #pragma unroll
    for (int w = 0; w < 4; ++w)
        if (wok[w])
            *(f32x2*)&ob[(wbase + w) * 256 + 2 * oa2] =
                f32x2{scaleA * preA[w], scaleB * preB[w]};
}

extern "C" void kernel_launch(void* const* d_in, const int* in_sizes, int n_in,
                              void* d_out, int out_size, void* d_ws, size_t ws_size,
                              hipStream_t stream)
{
    const float* x    = (const float*)d_in[0];  // [32,32,32,8,16] (raw-reshape view)
    const float* Wt   = (const float*)d_in[1];  // [16,3,3,1,256] = [144][256]
    const float* bias = (const float*)d_in[2];  // [16,16,1,1]
    float* out = (float*)d_out;                 // [32,30,30,16,16]
    _Float16* wt_h = (_Float16*)d_ws;           // [256][144] fp16 = 73,728 B

    prep_wt_kernel<<<dim3(144), 256, 0, stream>>>(Wt, wt_h);
    fused_kernel<<<dim3(960), 1024, 0, stream>>>(x, wt_h, bias, out);
}